// Round 1
// baseline (195.239 us; speedup 1.0000x reference)
//
#include <hip/hip_runtime.h>

#define Bn   4
#define Nn   1024
#define Mn   100
#define NB   25
#define FEAT 50
#define Hn   100
#define PIc  3.1415926f
#define RMAXc 6.0f
#define RSTEP (5.5f / 24.0f)

// ---------------------------------------------------------------- feat ----
__global__ __launch_bounds__(128) void feat_kernel(
    const int* __restrict__ itype, const int* __restrict__ nlist,
    const float* __restrict__ dR, float* __restrict__ feat)
{
    const int atom = blockIdx.x;           // b*N + n
    const int b = atom >> 10;              // / Nn
    const int t = threadIdx.x;

    __shared__ float rsh[Mn];
    __shared__ float csh[Mn];
    __shared__ int   tsh[Mn];

    if (t < Mn) {
        float r = dR[((size_t)atom * Mn + t) * 4 + 0];
        int v = nlist[(size_t)atom * Mn + t];
        int tt = -1;
        if (v > 0) tt = (itype[b * Nn + (v - 1)] == 8) ? 1 : 0;
        if (!(r < RMAXc && r > 0.0f)) tt = -1;
        rsh[t] = r;
        csh[t] = 0.5f * cosf(PIc * r) + 0.5f;
        tsh[t] = tt;
    }
    __syncthreads();

    if (t < FEAT) {
        const int tt = t / NB;
        const int k  = t - tt * NB;
        const float rk = 0.5f + k * RSTEP;
        float acc = 0.0f;
        for (int m = 0; m < Mn; ++m) {
            if (tsh[m] == tt) {
                float d = rsh[m] - rk;
                acc += expf(-d * d) * csh[m];
            }
        }
        feat[(size_t)atom * FEAT + t] = acc;
    }
}

// ----------------------------------------------------------------- mlp ----
__global__ __launch_bounds__(128) void mlp_kernel(
    const float* __restrict__ feat, const int* __restrict__ itype,
    const float* __restrict__ W0, const float* __restrict__ B0,
    const float* __restrict__ W1, const float* __restrict__ B1,
    const float* __restrict__ W2, const float* __restrict__ B2,
    const float* __restrict__ W3, const float* __restrict__ B3,
    float* __restrict__ Ei, float* __restrict__ Etot, float* __restrict__ dE)
{
    const int atom = blockIdx.x;
    const int b = atom >> 10;
    const int tnet = (itype[atom] == 8) ? 1 : 0;
    const int j = threadIdx.x;

    __shared__ float fsh[FEAT];
    __shared__ float xs[Hn];
    __shared__ float dzs[Hn];
    __shared__ float dx1s[Hn];
    __shared__ float red[128];

    if (j < FEAT) fsh[j] = feat[(size_t)atom * FEAT + j];
    __syncthreads();

    const float* w0 = W0 + (size_t)tnet * FEAT * Hn;
    const float* w1 = W1 + (size_t)tnet * Hn * Hn;
    const float* w2 = W2 + (size_t)tnet * Hn * Hn;
    const float* w3 = W3 + (size_t)tnet * Hn;

    float h0 = 0.f, h1 = 0.f, h2 = 0.f;
    float x1j = 0.f, x2j = 0.f, x3j = 0.f;

    if (j < Hn) {
        float z = B0[tnet * Hn + j];
        #pragma unroll 10
        for (int f = 0; f < FEAT; ++f) z += fsh[f] * w0[f * Hn + j];
        h0 = tanhf(z);
        x1j = h0 + fsh[(j < FEAT) ? j : (j - FEAT)];
        xs[j] = x1j;
    }
    __syncthreads();

    if (j < Hn) {
        float z = B1[tnet * Hn + j];
        #pragma unroll 10
        for (int i = 0; i < Hn; ++i) z += xs[i] * w1[i * Hn + j];
        h1 = tanhf(z);
        x2j = h1 + x1j;
    }
    __syncthreads();
    if (j < Hn) xs[j] = x2j;
    __syncthreads();

    if (j < Hn) {
        float z = B2[tnet * Hn + j];
        #pragma unroll 10
        for (int i = 0; i < Hn; ++i) z += xs[i] * w2[i * Hn + j];
        h2 = tanhf(z);
        x3j = h2 + x2j;
    }

    // Ei = x3 . W3 + b3  (block reduce over 100 lanes)
    red[j] = (j < Hn) ? x3j * w3[j] : 0.0f;
    __syncthreads();
    for (int s = 64; s > 0; s >>= 1) {
        if (j < s) red[j] += red[j + s];
        __syncthreads();
    }
    if (j == 0) {
        float ei = red[0] + B3[tnet];
        Ei[atom] = ei;
        atomicAdd(&Etot[b], ei);
    }

    // ---- backward: dE/dfeat ----
    float dx3 = (j < Hn) ? w3[j] : 0.0f;
    if (j < Hn) dzs[j] = dx3 * (1.0f - h2 * h2);
    __syncthreads();

    float dx2 = 0.0f;
    if (j < Hn) {
        dx2 = dx3;
        #pragma unroll 10
        for (int jj = 0; jj < Hn; ++jj) dx2 += w2[j * Hn + jj] * dzs[jj];
    }
    __syncthreads();
    if (j < Hn) dzs[j] = dx2 * (1.0f - h1 * h1);
    __syncthreads();

    float dx1 = 0.0f;
    if (j < Hn) {
        dx1 = dx2;
        #pragma unroll 10
        for (int jj = 0; jj < Hn; ++jj) dx1 += w1[j * Hn + jj] * dzs[jj];
        dx1s[j] = dx1;
    }
    __syncthreads();
    if (j < Hn) dzs[j] = dx1 * (1.0f - h0 * h0);
    __syncthreads();

    if (j < FEAT) {
        float g = dx1s[j] + dx1s[j + FEAT];
        #pragma unroll 10
        for (int jj = 0; jj < Hn; ++jj) g += w0[j * Hn + jj] * dzs[jj];
        dE[(size_t)atom * FEAT + j] = g;
    }
}

// --------------------------------------------------------------- force ----
__global__ __launch_bounds__(128) void force_kernel(
    const int* __restrict__ itype, const int* __restrict__ nlist,
    const float* __restrict__ dR, const float* __restrict__ dE,
    float* __restrict__ Force)
{
    const int atom = blockIdx.x;
    const int b = atom >> 10;
    const int t = threadIdx.x;

    __shared__ float desh[FEAT];
    __shared__ float rx[128], ry[128], rz[128];

    if (t < FEAT) desh[t] = dE[(size_t)atom * FEAT + t];
    __syncthreads();

    float fx = 0.f, fy = 0.f, fz = 0.f;
    if (t < Mn) {
        const float* p = dR + ((size_t)atom * Mn + t) * 4;
        float r = p[0];
        int v = nlist[(size_t)atom * Mn + t];
        int tt = -1;
        if (v > 0) tt = (itype[b * Nn + (v - 1)] == 8) ? 1 : 0;
        if (tt >= 0 && r < RMAXc && r > 0.0f) {
            float c  = 0.5f * cosf(PIc * r) + 0.5f;
            float dc = -0.5f * PIc * sinf(PIc * r);
            float s = 0.0f;
            const float* de = desh + tt * NB;
            #pragma unroll
            for (int k = 0; k < NB; ++k) {
                float d = r - (0.5f + k * RSTEP);
                float e = expf(-d * d);
                s += de[k] * (e * (dc - 2.0f * d * c));
            }
            float inv = 1.0f / r;
            fx = s * p[1] * inv;
            fy = s * p[2] * inv;
            fz = s * p[3] * inv;
            size_t dst = (size_t)(b * Nn + (v - 1)) * 3;
            atomicAdd(&Force[dst + 0], fx);
            atomicAdd(&Force[dst + 1], fy);
            atomicAdd(&Force[dst + 2], fz);
        }
    }
    rx[t] = fx; ry[t] = fy; rz[t] = fz;
    __syncthreads();
    for (int s = 64; s > 0; s >>= 1) {
        if (t < s) { rx[t] += rx[t + s]; ry[t] += ry[t + s]; rz[t] += rz[t + s]; }
        __syncthreads();
    }
    if (t == 0) {
        atomicAdd(&Force[(size_t)atom * 3 + 0], -rx[0]);
        atomicAdd(&Force[(size_t)atom * 3 + 1], -ry[0]);
        atomicAdd(&Force[(size_t)atom * 3 + 2], -rz[0]);
    }
}

// -------------------------------------------------------------- launch ----
extern "C" void kernel_launch(void* const* d_in, const int* in_sizes, int n_in,
                              void* d_out, int out_size, void* d_ws, size_t ws_size,
                              hipStream_t stream)
{
    const int*   itype = (const int*)d_in[0];
    const int*   nlist = (const int*)d_in[1];
    const float* dR    = (const float*)d_in[2];
    const float* W0 = (const float*)d_in[3];  const float* B0 = (const float*)d_in[4];
    const float* W1 = (const float*)d_in[5];  const float* B1 = (const float*)d_in[6];
    const float* W2 = (const float*)d_in[7];  const float* B2 = (const float*)d_in[8];
    const float* W3 = (const float*)d_in[9];  const float* B3 = (const float*)d_in[10];

    float* out   = (float*)d_out;
    float* Etot  = out;                    // [B,1]      -> 4
    float* Ei    = out + Bn;               // [B,N,1]    -> 4096
    float* Force = out + Bn + Bn * Nn;     // [B,N,3]    -> 12288

    float* feat = (float*)d_ws;                       // B*N*50 floats
    float* dE   = feat + (size_t)Bn * Nn * FEAT;      // B*N*50 floats

    hipMemsetAsync(d_out, 0, (size_t)out_size * sizeof(float), stream);

    const int atoms = Bn * Nn;
    feat_kernel <<<atoms, 128, 0, stream>>>(itype, nlist, dR, feat);
    mlp_kernel  <<<atoms, 128, 0, stream>>>(feat, itype, W0, B0, W1, B1, W2, B2, W3, B3,
                                            Ei, Etot, dE);
    force_kernel<<<atoms, 128, 0, stream>>>(itype, nlist, dR, dE, Force);
}

// Round 2
// 141.934 us; speedup vs baseline: 1.3756x; 1.3756x over previous
//
#include <hip/hip_runtime.h>

#define Bn   4
#define Nn   1024
#define Mn   100
#define NB   25
#define FEAT 50
#define Hn   100
#define PIc  3.1415926f
#define RMAXc 6.0f
#define RSTEP (5.5f / 24.0f)
#define AT   8        // atoms per MLP block
#define GPB  32       // force blocks (groups) per batch
#define CPG  32       // centers per group (GPB*CPG == Nn)
#define FTHREADS 512

// ---------------------------------------------------------------- feat ----
__global__ __launch_bounds__(128) void feat_kernel(
    const int* __restrict__ itype, const int* __restrict__ nlist,
    const float* __restrict__ dR, float* __restrict__ feat)
{
    const int atom = blockIdx.x;
    const int b = atom >> 10;
    const int t = threadIdx.x;

    __shared__ float rsh[Mn];
    __shared__ float csh[Mn];
    __shared__ int   tsh[Mn];

    if (t < Mn) {
        float r = dR[((size_t)atom * Mn + t) * 4 + 0];
        int v = nlist[(size_t)atom * Mn + t];
        int tt = -1;
        if (v > 0) tt = (itype[b * Nn + (v - 1)] == 8) ? 1 : 0;
        if (!(r < RMAXc && r > 0.0f)) tt = -1;
        rsh[t] = r;
        csh[t] = 0.5f * __cosf(PIc * r) + 0.5f;
        tsh[t] = tt;
    }
    __syncthreads();

    if (t < FEAT) {
        const int tt = t / NB;
        const int k  = t - tt * NB;
        const float rk = 0.5f + k * RSTEP;
        float acc = 0.0f;
        for (int m = 0; m < Mn; ++m) {
            if (tsh[m] == tt) {
                float d = rsh[m] - rk;
                acc += __expf(-d * d) * csh[m];
            }
        }
        feat[(size_t)atom * FEAT + t] = acc;
    }
}

// ----------------------------------------------------------------- mlp ----
// One block = AT atoms; thread j owns hidden unit j for all AT atoms.
// Weight element loaded once (both types), reused AT times.
__global__ __launch_bounds__(128) void mlp_kernel(
    const float* __restrict__ feat, const int* __restrict__ itype,
    const float* __restrict__ W0, const float* __restrict__ B0,
    const float* __restrict__ W1, const float* __restrict__ B1,
    const float* __restrict__ W2, const float* __restrict__ B2,
    const float* __restrict__ W3, const float* __restrict__ B3,
    float* __restrict__ Ei, float* __restrict__ dE)
{
    const int base = blockIdx.x * AT;
    const int j = threadIdx.x;

    __shared__ float fsh[AT][FEAT];
    __shared__ float xs[AT][Hn];
    __shared__ float dzs[AT][Hn];
    __shared__ float dx1s[AT][Hn];
    __shared__ float red[AT][128];

    int ty[AT];
    #pragma unroll
    for (int a = 0; a < AT; ++a) ty[a] = (itype[base + a] == 8) ? 1 : 0;

    for (int idx = j; idx < AT * FEAT; idx += 128)
        ((float*)fsh)[idx] = feat[(size_t)base * FEAT + idx];
    __syncthreads();

    const float* w0a = W0;  const float* w0b = W0 + FEAT * Hn;
    const float* w1a = W1;  const float* w1b = W1 + Hn * Hn;
    const float* w2a = W2;  const float* w2b = W2 + Hn * Hn;
    const float* w3a = W3;  const float* w3b = W3 + Hn;

    float h0[AT], h1[AT], h2[AT], x1[AT], x3[AT], z[AT];

    // ---- layer 0 ----
    if (j < Hn) {
        #pragma unroll
        for (int a = 0; a < AT; ++a) z[a] = ty[a] ? B0[Hn + j] : B0[j];
        #pragma unroll 10
        for (int f = 0; f < FEAT; ++f) {
            float wa = w0a[f * Hn + j], wb = w0b[f * Hn + j];
            #pragma unroll
            for (int a = 0; a < AT; ++a) z[a] += fsh[a][f] * (ty[a] ? wb : wa);
        }
        const int jf = (j < FEAT) ? j : j - FEAT;
        #pragma unroll
        for (int a = 0; a < AT; ++a) {
            h0[a] = tanhf(z[a]);
            x1[a] = h0[a] + fsh[a][jf];
            xs[a][j] = x1[a];
        }
    }
    __syncthreads();

    // ---- layer 1 ----
    float x2[AT];
    if (j < Hn) {
        #pragma unroll
        for (int a = 0; a < AT; ++a) z[a] = ty[a] ? B1[Hn + j] : B1[j];
        #pragma unroll 10
        for (int i = 0; i < Hn; ++i) {
            float wa = w1a[i * Hn + j], wb = w1b[i * Hn + j];
            #pragma unroll
            for (int a = 0; a < AT; ++a) z[a] += xs[a][i] * (ty[a] ? wb : wa);
        }
        #pragma unroll
        for (int a = 0; a < AT; ++a) { h1[a] = tanhf(z[a]); x2[a] = h1[a] + x1[a]; }
    }
    __syncthreads();
    if (j < Hn) {
        #pragma unroll
        for (int a = 0; a < AT; ++a) xs[a][j] = x2[a];
    }
    __syncthreads();

    // ---- layer 2 ----
    if (j < Hn) {
        #pragma unroll
        for (int a = 0; a < AT; ++a) z[a] = ty[a] ? B2[Hn + j] : B2[j];
        #pragma unroll 10
        for (int i = 0; i < Hn; ++i) {
            float wa = w2a[i * Hn + j], wb = w2b[i * Hn + j];
            #pragma unroll
            for (int a = 0; a < AT; ++a) z[a] += xs[a][i] * (ty[a] ? wb : wa);
        }
        #pragma unroll
        for (int a = 0; a < AT; ++a) { h2[a] = tanhf(z[a]); x3[a] = h2[a] + x2[a]; }
    }

    // ---- Ei = x3 . w3 + b3  (parallel tree reduce for all AT atoms) ----
    {
        #pragma unroll
        for (int a = 0; a < AT; ++a)
            red[a][j] = (j < Hn) ? x3[a] * (ty[a] ? w3b[j] : w3a[j]) : 0.0f;
        __syncthreads();
        for (int s = 64; s > 0; s >>= 1) {
            if (j < s) {
                #pragma unroll
                for (int a = 0; a < AT; ++a) red[a][j] += red[a][j + s];
            }
            __syncthreads();
        }
        if (j < AT) {
            int tj = (itype[base + j] == 8) ? 1 : 0;
            Ei[base + j] = red[j][0] + B3[tj];
        }
    }

    // ---- backward ----
    if (j < Hn) {
        #pragma unroll
        for (int a = 0; a < AT; ++a) {
            float dx3 = ty[a] ? w3b[j] : w3a[j];
            dzs[a][j] = dx3 * (1.0f - h2[a] * h2[a]);
        }
    }
    __syncthreads();

    float dx2[AT];
    if (j < Hn) {
        #pragma unroll
        for (int a = 0; a < AT; ++a) dx2[a] = ty[a] ? w3b[j] : w3a[j];
        #pragma unroll 10
        for (int jj = 0; jj < Hn; ++jj) {
            float wa = w2a[j * Hn + jj], wb = w2b[j * Hn + jj];
            #pragma unroll
            for (int a = 0; a < AT; ++a) dx2[a] += (ty[a] ? wb : wa) * dzs[a][jj];
        }
    }
    __syncthreads();
    if (j < Hn) {
        #pragma unroll
        for (int a = 0; a < AT; ++a) dzs[a][j] = dx2[a] * (1.0f - h1[a] * h1[a]);
    }
    __syncthreads();

    float dx1[AT];
    if (j < Hn) {
        #pragma unroll
        for (int a = 0; a < AT; ++a) dx1[a] = dx2[a];
        #pragma unroll 10
        for (int jj = 0; jj < Hn; ++jj) {
            float wa = w1a[j * Hn + jj], wb = w1b[j * Hn + jj];
            #pragma unroll
            for (int a = 0; a < AT; ++a) dx1[a] += (ty[a] ? wb : wa) * dzs[a][jj];
        }
        #pragma unroll
        for (int a = 0; a < AT; ++a) dx1s[a][j] = dx1[a];
    }
    __syncthreads();
    if (j < Hn) {
        #pragma unroll
        for (int a = 0; a < AT; ++a) dzs[a][j] = dx1[a] * (1.0f - h0[a] * h0[a]);
    }
    __syncthreads();

    if (j < FEAT) {
        float g[AT];
        #pragma unroll
        for (int a = 0; a < AT; ++a) g[a] = dx1s[a][j] + dx1s[a][j + FEAT];
        #pragma unroll 10
        for (int jj = 0; jj < Hn; ++jj) {
            float wa = w0a[j * Hn + jj], wb = w0b[j * Hn + jj];
            #pragma unroll
            for (int a = 0; a < AT; ++a) g[a] += (ty[a] ? wb : wa) * dzs[a][jj];
        }
        #pragma unroll
        for (int a = 0; a < AT; ++a) dE[((size_t)(base + a)) * FEAT + j] = g[a];
    }
}

// ---------------------------------------------------------------- etot ----
__global__ __launch_bounds__(256) void etot_kernel(
    const float* __restrict__ Ei, float* __restrict__ Etot)
{
    const int b = blockIdx.x, t = threadIdx.x;
    __shared__ float red[256];
    float s = 0.0f;
    for (int i = t; i < Nn; i += 256) s += Ei[b * Nn + i];
    red[t] = s;
    __syncthreads();
    for (int st = 128; st > 0; st >>= 1) {
        if (t < st) red[t] += red[t + st];
        __syncthreads();
    }
    if (t == 0) Etot[b] = red[0];
}

// --------------------------------------------------------------- force ----
// Block = one group of CPG centers of one batch. Accumulate ALL force
// contributions (center - and neighbor +) into an LDS array over the whole
// batch's atom range, then dump to a per-block partial. No global atomics.
__global__ __launch_bounds__(FTHREADS) void force_kernel(
    const int* __restrict__ itype, const int* __restrict__ nlist,
    const float* __restrict__ dR, const float* __restrict__ dE,
    float* __restrict__ partial)
{
    const int blk = blockIdx.x;        // Bn*GPB
    const int b = blk / GPB;
    const int g = blk - b * GPB;
    const int t = threadIdx.x;

    __shared__ float acc[(Nn + 1) * 3];
    __shared__ float desh[CPG][FEAT];

    for (int idx = t; idx < (Nn + 1) * 3; idx += FTHREADS) acc[idx] = 0.0f;
    for (int idx = t; idx < CPG * FEAT; idx += FTHREADS)
        ((float*)desh)[idx] = dE[((size_t)(b * Nn) + g * CPG) * FEAT + idx];
    __syncthreads();

    for (int p = t; p < CPG * Mn; p += FTHREADS) {
        int c = p / Mn, m = p - c * Mn;
        int n = g * CPG + c;                       // center index within batch
        size_t pair = (size_t)(b * Nn + n) * Mn + m;
        float4 q = ((const float4*)dR)[pair];
        int v = nlist[pair];
        if (v > 0) {
            float r = q.x;
            if (r < RMAXc && r > 0.0f) {
                int tt = (itype[b * Nn + v - 1] == 8) ? 1 : 0;
                float cw  = 0.5f * __cosf(PIc * r) + 0.5f;
                float dcw = -0.5f * PIc * __sinf(PIc * r);
                float s = 0.0f;
                const float* de = &desh[c][tt * NB];
                #pragma unroll
                for (int k = 0; k < NB; ++k) {
                    float d = r - (0.5f + k * RSTEP);
                    float e = __expf(-d * d);
                    s += de[k] * (e * dcw - 2.0f * d * e * cw);
                }
                float inv = 1.0f / r;
                float fx = s * q.y * inv, fy = s * q.z * inv, fz = s * q.w * inv;
                atomicAdd(&acc[v * 3 + 0], fx);
                atomicAdd(&acc[v * 3 + 1], fy);
                atomicAdd(&acc[v * 3 + 2], fz);
                atomicAdd(&acc[(n + 1) * 3 + 0], -fx);
                atomicAdd(&acc[(n + 1) * 3 + 1], -fy);
                atomicAdd(&acc[(n + 1) * 3 + 2], -fz);
            }
        }
    }
    __syncthreads();

    float* pout = partial + (size_t)blk * ((Nn + 1) * 3);
    for (int idx = t; idx < (Nn + 1) * 3; idx += FTHREADS) pout[idx] = acc[idx];
}

// ------------------------------------------------------------- freduce ----
__global__ __launch_bounds__(256) void freduce_kernel(
    const float* __restrict__ partial, float* __restrict__ Force)
{
    int idx = blockIdx.x * 256 + threadIdx.x;
    if (idx >= Bn * Nn * 3) return;
    int b = idx / (Nn * 3);
    int r = idx - b * (Nn * 3);
    int i = r / 3, ch = r - i * 3;
    float s = 0.0f;
    for (int g = 0; g < GPB; ++g)
        s += partial[((size_t)(b * GPB + g)) * ((Nn + 1) * 3) + (size_t)(i + 1) * 3 + ch];
    Force[idx] = s;
}

// -------------------------------------------------------------- launch ----
extern "C" void kernel_launch(void* const* d_in, const int* in_sizes, int n_in,
                              void* d_out, int out_size, void* d_ws, size_t ws_size,
                              hipStream_t stream)
{
    const int*   itype = (const int*)d_in[0];
    const int*   nlist = (const int*)d_in[1];
    const float* dR    = (const float*)d_in[2];
    const float* W0 = (const float*)d_in[3];  const float* B0 = (const float*)d_in[4];
    const float* W1 = (const float*)d_in[5];  const float* B1 = (const float*)d_in[6];
    const float* W2 = (const float*)d_in[7];  const float* B2 = (const float*)d_in[8];
    const float* W3 = (const float*)d_in[9];  const float* B3 = (const float*)d_in[10];

    float* out   = (float*)d_out;
    float* Etot  = out;                    // [B,1]
    float* Ei    = out + Bn;               // [B,N,1]
    float* Force = out + Bn + Bn * Nn;     // [B,N,3]

    float* feat    = (float*)d_ws;                          // 4096*50
    float* dE      = feat + (size_t)Bn * Nn * FEAT;         // 4096*50
    float* partial = dE + (size_t)Bn * Nn * FEAT;           // Bn*GPB*(Nn+1)*3

    const int atoms = Bn * Nn;
    feat_kernel   <<<atoms, 128, 0, stream>>>(itype, nlist, dR, feat);
    mlp_kernel    <<<atoms / AT, 128, 0, stream>>>(feat, itype, W0, B0, W1, B1,
                                                   W2, B2, W3, B3, Ei, dE);
    etot_kernel   <<<Bn, 256, 0, stream>>>(Ei, Etot);
    force_kernel  <<<Bn * GPB, FTHREADS, 0, stream>>>(itype, nlist, dR, dE, partial);
    freduce_kernel<<<(Bn * Nn * 3 + 255) / 256, 256, 0, stream>>>(partial, Force);
}

// Round 3
// 85.233 us; speedup vs baseline: 2.2906x; 1.6652x over previous
//
#include <hip/hip_runtime.h>

#define Bn   4
#define Nn   1024
#define Mn   100
#define NB   25
#define FEAT 50
#define Hn   100
#define PIc  3.1415926f
#define RMAXc 6.0f
#define RSTEP (5.5f / 24.0f)
#define AT   4        // atoms per MLP block (type-pure groups)
#define NATOMS (Bn * Nn)
#define ORDER_LEN (NATOMS + AT)          // 4100
#define MLP_BLOCKS (ORDER_LEN / AT)      // 1025
#define GPB  32       // force blocks per batch
#define CPG  32       // centers per force block
#define FTHREADS 512

__device__ __forceinline__ float fast_tanh(float x) {
    float ax = fabsf(x);
    float t  = __expf(-2.0f * ax);
    float r  = (1.0f - t) * __builtin_amdgcn_rcpf(1.0f + t);
    return copysignf(r, x);
}

// ---------------------------------------------------------------- sort ----
// Deterministic type partition: order[] = type-0 atom ids, pad to AT with -1,
// then type-1 atom ids, pad tail with -1. Single block, Hillis-Steele scan.
__global__ __launch_bounds__(1024) void sort_kernel(
    const int* __restrict__ itype, int* __restrict__ order)
{
    const int t = threadIdx.x;
    __shared__ int scan[1024];

    for (int i = t; i < ORDER_LEN; i += 1024) order[i] = -1;

    int ty[4]; int c0 = 0;
    #pragma unroll
    for (int k = 0; k < 4; ++k) {
        int ty_ = (itype[t * 4 + k] == 8) ? 1 : 0;
        ty[k] = ty_; c0 += 1 - ty_;
    }
    scan[t] = c0;
    __syncthreads();
    for (int off = 1; off < 1024; off <<= 1) {
        int v = scan[t];
        int add = (t >= off) ? scan[t - off] : 0;
        __syncthreads();
        scan[t] = v + add;
        __syncthreads();
    }
    const int total0 = scan[1023];
    const int ex0 = scan[t] - c0;          // excl. prefix of type-0 count
    const int ex1 = 4 * t - ex0;           // excl. prefix of type-1 count
    const int pad0 = (total0 + (AT - 1)) & ~(AT - 1);
    int p0 = ex0, p1 = pad0 + ex1;
    #pragma unroll
    for (int k = 0; k < 4; ++k) {
        int idx = t * 4 + k;
        if (ty[k] == 0) order[p0++] = idx; else order[p1++] = idx;
    }
}

// ---------------------------------------------------------------- feat ----
__global__ __launch_bounds__(128) void feat_kernel(
    const int* __restrict__ itype, const int* __restrict__ nlist,
    const float* __restrict__ dR, float* __restrict__ feat)
{
    const int atom = blockIdx.x;
    const int b = atom >> 10;
    const int t = threadIdx.x;

    __shared__ float rsh[Mn];
    __shared__ float csh[Mn];
    __shared__ int   tsh[Mn];

    if (t < Mn) {
        float r = dR[((size_t)atom * Mn + t) * 4 + 0];
        int v = nlist[(size_t)atom * Mn + t];
        int tt = -1;
        if (v > 0) tt = (itype[b * Nn + (v - 1)] == 8) ? 1 : 0;
        if (!(r < RMAXc && r > 0.0f)) tt = -1;
        rsh[t] = r;
        csh[t] = 0.5f * __cosf(PIc * r) + 0.5f;
        tsh[t] = tt;
    }
    __syncthreads();

    if (t < FEAT) {
        const int tt = t / NB;
        const int k  = t - tt * NB;
        const float rk = 0.5f + k * RSTEP;
        float acc = 0.0f;
        for (int m = 0; m < Mn; ++m) {
            if (tsh[m] == tt) {
                float d = rsh[m] - rk;
                acc += __expf(-d * d) * csh[m];
            }
        }
        feat[(size_t)atom * FEAT + t] = acc;
    }
}

// ----------------------------------------------------------------- mlp ----
// Block = AT same-type atoms (from order[]); thread j owns hidden unit j.
__global__ __launch_bounds__(128) void mlp_kernel(
    const float* __restrict__ feat, const int* __restrict__ itype,
    const int* __restrict__ order,
    const float* __restrict__ W0, const float* __restrict__ B0,
    const float* __restrict__ W1, const float* __restrict__ B1,
    const float* __restrict__ W2, const float* __restrict__ B2,
    const float* __restrict__ W3, const float* __restrict__ B3,
    float* __restrict__ Ei, float* __restrict__ dE)
{
    const int base = blockIdx.x * AT;
    const int j = threadIdx.x;

    int aidx[AT];
    #pragma unroll
    for (int a = 0; a < AT; ++a) aidx[a] = order[base + a];
    if (aidx[0] < 0 && aidx[1] < 0 && aidx[2] < 0 && aidx[3] < 0) return;
    int first = aidx[0];
    #pragma unroll
    for (int a = AT - 1; a >= 0; --a) if (aidx[a] >= 0) first = aidx[a];
    const int tnet = (itype[first] == 8) ? 1 : 0;

    __shared__ float fsh[AT][FEAT];
    __shared__ float xs[AT][Hn];
    __shared__ float dzs[AT][Hn];
    __shared__ float dx1s[AT][Hn];
    __shared__ float red[AT][128];

    for (int idx = j; idx < AT * FEAT; idx += 128) {
        int a = idx / FEAT, f = idx - a * FEAT;
        fsh[a][f] = (aidx[a] >= 0) ? feat[(size_t)aidx[a] * FEAT + f] : 0.0f;
    }
    __syncthreads();

    const float* w0 = W0 + (size_t)tnet * FEAT * Hn;
    const float* w1 = W1 + (size_t)tnet * Hn * Hn;
    const float* w2 = W2 + (size_t)tnet * Hn * Hn;
    const float* w3 = W3 + (size_t)tnet * Hn;

    float h0[AT], h1[AT], h2[AT], x1[AT], x3[AT], z[AT];

    // ---- layer 0 ----
    if (j < Hn) {
        const float b0v = B0[tnet * Hn + j];
        #pragma unroll
        for (int a = 0; a < AT; ++a) z[a] = b0v;
        #pragma unroll 10
        for (int f = 0; f < FEAT; ++f) {
            float w = w0[f * Hn + j];
            #pragma unroll
            for (int a = 0; a < AT; ++a) z[a] += fsh[a][f] * w;
        }
        const int jf = (j < FEAT) ? j : j - FEAT;
        #pragma unroll
        for (int a = 0; a < AT; ++a) {
            h0[a] = fast_tanh(z[a]);
            x1[a] = h0[a] + fsh[a][jf];
            xs[a][j] = x1[a];
        }
    }
    __syncthreads();

    // ---- layer 1 ----
    float x2[AT];
    if (j < Hn) {
        const float b1v = B1[tnet * Hn + j];
        #pragma unroll
        for (int a = 0; a < AT; ++a) z[a] = b1v;
        #pragma unroll 10
        for (int i = 0; i < Hn; ++i) {
            float w = w1[i * Hn + j];
            #pragma unroll
            for (int a = 0; a < AT; ++a) z[a] += xs[a][i] * w;
        }
        #pragma unroll
        for (int a = 0; a < AT; ++a) { h1[a] = fast_tanh(z[a]); x2[a] = h1[a] + x1[a]; }
    }
    __syncthreads();
    if (j < Hn) {
        #pragma unroll
        for (int a = 0; a < AT; ++a) xs[a][j] = x2[a];
    }
    __syncthreads();

    // ---- layer 2 ----
    if (j < Hn) {
        const float b2v = B2[tnet * Hn + j];
        #pragma unroll
        for (int a = 0; a < AT; ++a) z[a] = b2v;
        #pragma unroll 10
        for (int i = 0; i < Hn; ++i) {
            float w = w2[i * Hn + j];
            #pragma unroll
            for (int a = 0; a < AT; ++a) z[a] += xs[a][i] * w;
        }
        #pragma unroll
        for (int a = 0; a < AT; ++a) { h2[a] = fast_tanh(z[a]); x3[a] = h2[a] + x2[a]; }
    }

    // ---- Ei ----
    {
        const float w3j = (j < Hn) ? w3[j] : 0.0f;
        #pragma unroll
        for (int a = 0; a < AT; ++a) red[a][j] = (j < Hn) ? x3[a] * w3j : 0.0f;
        __syncthreads();
        for (int s = 64; s > 0; s >>= 1) {
            if (j < s) {
                #pragma unroll
                for (int a = 0; a < AT; ++a) red[a][j] += red[a][j + s];
            }
            __syncthreads();
        }
        if (j < AT && aidx[j] >= 0)
            Ei[aidx[j]] = red[j][0] + B3[tnet];
    }

    // ---- backward ----
    if (j < Hn) {
        const float w3j = w3[j];
        #pragma unroll
        for (int a = 0; a < AT; ++a) dzs[a][j] = w3j * (1.0f - h2[a] * h2[a]);
    }
    __syncthreads();

    float dx2[AT];
    if (j < Hn) {
        const float w3j = w3[j];
        #pragma unroll
        for (int a = 0; a < AT; ++a) dx2[a] = w3j;
        #pragma unroll 10
        for (int jj = 0; jj < Hn; ++jj) {
            float w = w2[j * Hn + jj];
            #pragma unroll
            for (int a = 0; a < AT; ++a) dx2[a] += w * dzs[a][jj];
        }
    }
    __syncthreads();
    if (j < Hn) {
        #pragma unroll
        for (int a = 0; a < AT; ++a) dzs[a][j] = dx2[a] * (1.0f - h1[a] * h1[a]);
    }
    __syncthreads();

    float dx1[AT];
    if (j < Hn) {
        #pragma unroll
        for (int a = 0; a < AT; ++a) dx1[a] = dx2[a];
        #pragma unroll 10
        for (int jj = 0; jj < Hn; ++jj) {
            float w = w1[j * Hn + jj];
            #pragma unroll
            for (int a = 0; a < AT; ++a) dx1[a] += w * dzs[a][jj];
        }
        #pragma unroll
        for (int a = 0; a < AT; ++a) dx1s[a][j] = dx1[a];
    }
    __syncthreads();
    if (j < Hn) {
        #pragma unroll
        for (int a = 0; a < AT; ++a) dzs[a][j] = dx1[a] * (1.0f - h0[a] * h0[a]);
    }
    __syncthreads();

    if (j < FEAT) {
        float g[AT];
        #pragma unroll
        for (int a = 0; a < AT; ++a) g[a] = dx1s[a][j] + dx1s[a][j + FEAT];
        #pragma unroll 10
        for (int jj = 0; jj < Hn; ++jj) {
            float w = w0[j * Hn + jj];
            #pragma unroll
            for (int a = 0; a < AT; ++a) g[a] += w * dzs[a][jj];
        }
        #pragma unroll
        for (int a = 0; a < AT; ++a)
            if (aidx[a] >= 0) dE[(size_t)aidx[a] * FEAT + j] = g[a];
    }
}

// ---------------------------------------------------------------- etot ----
__global__ __launch_bounds__(256) void etot_kernel(
    const float* __restrict__ Ei, float* __restrict__ Etot)
{
    const int b = blockIdx.x, t = threadIdx.x;
    __shared__ float red[256];
    float s = 0.0f;
    for (int i = t; i < Nn; i += 256) s += Ei[b * Nn + i];
    red[t] = s;
    __syncthreads();
    for (int st = 128; st > 0; st >>= 1) {
        if (t < st) red[t] += red[t + st];
        __syncthreads();
    }
    if (t == 0) Etot[b] = red[0];
}

// --------------------------------------------------------------- force ----
__global__ __launch_bounds__(FTHREADS) void force_kernel(
    const int* __restrict__ itype, const int* __restrict__ nlist,
    const float* __restrict__ dR, const float* __restrict__ dE,
    float* __restrict__ partial)
{
    const int blk = blockIdx.x;
    const int b = blk / GPB;
    const int g = blk - b * GPB;
    const int t = threadIdx.x;

    __shared__ float acc[(Nn + 1) * 3];
    __shared__ float desh[CPG][FEAT];

    for (int idx = t; idx < (Nn + 1) * 3; idx += FTHREADS) acc[idx] = 0.0f;
    for (int idx = t; idx < CPG * FEAT; idx += FTHREADS)
        ((float*)desh)[idx] = dE[((size_t)(b * Nn) + g * CPG) * FEAT + idx];
    __syncthreads();

    for (int p = t; p < CPG * Mn; p += FTHREADS) {
        int c = p / Mn, m = p - c * Mn;
        int n = g * CPG + c;
        size_t pair = (size_t)(b * Nn + n) * Mn + m;
        float4 q = ((const float4*)dR)[pair];
        int v = nlist[pair];
        if (v > 0) {
            float r = q.x;
            if (r < RMAXc && r > 0.0f) {
                int tt = (itype[b * Nn + v - 1] == 8) ? 1 : 0;
                float cw  = 0.5f * __cosf(PIc * r) + 0.5f;
                float dcw = -0.5f * PIc * __sinf(PIc * r);
                float s = 0.0f;
                const float* de = &desh[c][tt * NB];
                #pragma unroll
                for (int k = 0; k < NB; ++k) {
                    float d = r - (0.5f + k * RSTEP);
                    float e = __expf(-d * d);
                    s += de[k] * (e * dcw - 2.0f * d * e * cw);
                }
                float inv = 1.0f / r;
                float fx = s * q.y * inv, fy = s * q.z * inv, fz = s * q.w * inv;
                atomicAdd(&acc[v * 3 + 0], fx);
                atomicAdd(&acc[v * 3 + 1], fy);
                atomicAdd(&acc[v * 3 + 2], fz);
                atomicAdd(&acc[(n + 1) * 3 + 0], -fx);
                atomicAdd(&acc[(n + 1) * 3 + 1], -fy);
                atomicAdd(&acc[(n + 1) * 3 + 2], -fz);
            }
        }
    }
    __syncthreads();

    float* pout = partial + (size_t)blk * ((Nn + 1) * 3);
    for (int idx = t; idx < (Nn + 1) * 3; idx += FTHREADS) pout[idx] = acc[idx];
}

// ------------------------------------------------------------- freduce ----
__global__ __launch_bounds__(256) void freduce_kernel(
    const float* __restrict__ partial, float* __restrict__ Force)
{
    int idx = blockIdx.x * 256 + threadIdx.x;
    if (idx >= Bn * Nn * 3) return;
    int b = idx / (Nn * 3);
    int r = idx - b * (Nn * 3);
    int i = r / 3, ch = r - i * 3;
    float s = 0.0f;
    for (int g = 0; g < GPB; ++g)
        s += partial[((size_t)(b * GPB + g)) * ((Nn + 1) * 3) + (size_t)(i + 1) * 3 + ch];
    Force[idx] = s;
}

// -------------------------------------------------------------- launch ----
extern "C" void kernel_launch(void* const* d_in, const int* in_sizes, int n_in,
                              void* d_out, int out_size, void* d_ws, size_t ws_size,
                              hipStream_t stream)
{
    const int*   itype = (const int*)d_in[0];
    const int*   nlist = (const int*)d_in[1];
    const float* dR    = (const float*)d_in[2];
    const float* W0 = (const float*)d_in[3];  const float* B0 = (const float*)d_in[4];
    const float* W1 = (const float*)d_in[5];  const float* B1 = (const float*)d_in[6];
    const float* W2 = (const float*)d_in[7];  const float* B2 = (const float*)d_in[8];
    const float* W3 = (const float*)d_in[9];  const float* B3 = (const float*)d_in[10];

    float* out   = (float*)d_out;
    float* Etot  = out;                    // [B,1]
    float* Ei    = out + Bn;               // [B,N,1]
    float* Force = out + Bn + Bn * Nn;     // [B,N,3]

    float* feat    = (float*)d_ws;                          // 4096*50
    float* dE      = feat + (size_t)NATOMS * FEAT;          // 4096*50
    float* partial = dE + (size_t)NATOMS * FEAT;            // Bn*GPB*(Nn+1)*3
    int*   order   = (int*)(partial + (size_t)Bn * GPB * (Nn + 1) * 3);

    sort_kernel   <<<1, 1024, 0, stream>>>(itype, order);
    feat_kernel   <<<NATOMS, 128, 0, stream>>>(itype, nlist, dR, feat);
    mlp_kernel    <<<MLP_BLOCKS, 128, 0, stream>>>(feat, itype, order,
                                                   W0, B0, W1, B1, W2, B2, W3, B3,
                                                   Ei, dE);
    etot_kernel   <<<Bn, 256, 0, stream>>>(Ei, Etot);
    force_kernel  <<<Bn * GPB, FTHREADS, 0, stream>>>(itype, nlist, dR, dE, partial);
    freduce_kernel<<<(Bn * Nn * 3 + 255) / 256, 256, 0, stream>>>(partial, Force);
}